// Round 2
// baseline (133.473 us; speedup 1.0000x reference)
//
#include <hip/hip_runtime.h>
#include <math.h>

// Problem: M=256 positives, 3M=768 negatives, NUM_GT=32,
// proto (4,128,128), maps (*,64,64), gt_masks (32,512,512).
//
// Mask-loss restructure (verified exact rounds 1-7):
//   mean(bce_m) = (1/512^2) * [ 16 * sum_{hw in 128^2} softplus(L_m[hw])
//                               - dot(coef_m, T[gt_m]) ]
//   T[g,p] = sum_{512^2} gt_masks[g] * proto[p, y/4, x/4]
//
// Structure: ONE dispatch, zero hot atomics.
// Lessons:
//  - R2-3: far-atomics funneled through one line across 8 XCDs serialize
//    (~25 us) — publish via disjoint plain stores.
//  - R6: nontemporal loads on the gt_masks stream regressed (+9 us): L3 was
//    absorbing ~half the 33.5 MB stream; keep default cache policy.
//  - R8: final made a pure dense combine; cls/loc runs in tmat's shadow.
//  - R9: tmat thread owns (col, 8 rows): rows sharing a proto cell summed
//    BEFORE multiply (8 proto loads / 8 FMA per thread); 8 unrolled
//    independent mask loads; 1024 tmat blocks. Neutral-within-noise vs R8
//    (fill-speed noise dominates ±3 us); kept for lower instruction count.
//  - R10 (this round): fuse the final combine into the worker dispatch.
//    Per-block publish: plain stores -> __threadfence (agent release:
//    wbl2) -> two write-through agent-scope flag stores (double magic
//    M1^i / M2^i: a uniform poison can never satisfy both; no counter =
//    no zero-init dispatch; stale flags after a skipped re-poison still
//    give correct results since producers rewrite identical values).
//    Reducer = LAST block: computes cls/loc locally (CL never touches
//    global), polls flags with agent-scope loads, __threadfence, then
//    combines via agent-scope data loads. No producer waits on the
//    reducer -> deadlock-free at any occupancy. Saves k_final dispatch +
//    graph gap (~4 us predicted).
//
//   k_all (1281 blocks): [0,1024): 16-row tmat slab partials -> Tpart;
//                        [1024,1280): per-m softplus -> SP, coef -> C4;
//                        1280: cls+loc, poll flags, dense combine -> out.

#define INV_TOTAL (1.0f / (262144.0f * 256.0f))
#define MAGIC1 0xA5C3F00Du
#define MAGIC2 0x5A3C0FF2u

__device__ __forceinline__ float softplusf(float x) {
    return fmaxf(x, 0.0f) + __logf(1.0f + __expf(-fabsf(x)));
}

__device__ __forceinline__ float wave_sum(float v) {
    v += __shfl_down(v, 32);
    v += __shfl_down(v, 16);
    v += __shfl_down(v, 8);
    v += __shfl_down(v, 4);
    v += __shfl_down(v, 2);
    v += __shfl_down(v, 1);
    return v;
}

__device__ __forceinline__ float sum4(float4 v) {
    return (v.x + v.y) + (v.z + v.w);
}

__device__ __forceinline__ float ws_load(const float* p) {
    return __hip_atomic_load(p, __ATOMIC_RELAXED, __HIP_MEMORY_SCOPE_AGENT);
}

__global__ void __launch_bounds__(256)
k_all(const float* __restrict__ proto,
      const float* __restrict__ map_coef,
      const float* __restrict__ map_class,
      const float* __restrict__ map_box,
      const float* __restrict__ anchor_center,
      const float* __restrict__ anchor_box,
      const float* __restrict__ gt_boxes,
      const float* __restrict__ gt_masks,
      const int* __restrict__ pos_idx,
      const int* __restrict__ gt_idx,
      const int* __restrict__ neg_idx,
      float* __restrict__ Tpart,      // [1024*4] slab partials, slot = bid
      float* __restrict__ SP,         // [256] per-m softplus sums
      float* __restrict__ C4,         // [256*4] per-m coefs, dense
      unsigned* __restrict__ F1,      // [1280] completion flags (MAGIC1^i)
      unsigned* __restrict__ F2,      // [1280] completion flags (MAGIC2^i)
      float* __restrict__ out) {
    const int bid = blockIdx.x;
    const int t = threadIdx.x;
    const int wave = t >> 6, lane = t & 63;
    __shared__ float smem[4][4];

    if (bid < 1024) {
        // ---- tmat: partial T over a 16-row slab of gt_masks[g] ----
        // Thread owns float4-column k and 8 consecutive rows. Rows sharing a
        // proto cell (4 per cell) are summed BEFORE the proto multiply.
        const int g = bid >> 5, chunk = bid & 31;
        const float* mask = gt_masks + (size_t)g * (512 * 512);
        const int k  = t & 127;          // float4 column 0..127
        const int rg = t >> 7;           // row-group 0/1
        const int y0 = (chunk << 4) + (rg << 3);
        const float* mrow = mask + y0 * 512 + (k << 2);
        // 8 independent loads, all in flight
        float4 a0 = *reinterpret_cast<const float4*>(mrow);
        float4 a1 = *reinterpret_cast<const float4*>(mrow + 512);
        float4 a2 = *reinterpret_cast<const float4*>(mrow + 1024);
        float4 a3 = *reinterpret_cast<const float4*>(mrow + 1536);
        float4 a4 = *reinterpret_cast<const float4*>(mrow + 2048);
        float4 a5 = *reinterpret_cast<const float4*>(mrow + 2560);
        float4 a6 = *reinterpret_cast<const float4*>(mrow + 3072);
        float4 a7 = *reinterpret_cast<const float4*>(mrow + 3584);
        const float s0 = (sum4(a0) + sum4(a1)) + (sum4(a2) + sum4(a3));  // rows y0..y0+3
        const float s1 = (sum4(a4) + sum4(a5)) + (sum4(a6) + sum4(a7));  // rows y0+4..y0+7
        const int c0 = ((y0 >> 2) << 7) + k;   // proto cell for rows y0..y0+3
        const int c1 = c0 + 128;               // proto cell for rows y0+4..y0+7
        float tp0 = fmaf(s1, proto[c1],         s0 * proto[c0]);
        float tp1 = fmaf(s1, proto[16384 + c1], s0 * proto[16384 + c0]);
        float tp2 = fmaf(s1, proto[32768 + c1], s0 * proto[32768 + c0]);
        float tp3 = fmaf(s1, proto[49152 + c1], s0 * proto[49152 + c0]);
        tp0 = wave_sum(tp0); tp1 = wave_sum(tp1); tp2 = wave_sum(tp2); tp3 = wave_sum(tp3);
        if (lane == 0) { smem[wave][0] = tp0; smem[wave][1] = tp1; smem[wave][2] = tp2; smem[wave][3] = tp3; }
        __syncthreads();
        if (t < 4)
            Tpart[(bid << 2) + t] = smem[0][t] + smem[1][t] + smem[2][t] + smem[3][t];
        // t0..t3 store in ONE wave instruction; t0's fence drains the wave's
        // outstanding stores, then write-through flags publish device-wide.
        if (t == 0) {
            __threadfence();
            __hip_atomic_store(&F1[bid], MAGIC1 ^ (unsigned)bid, __ATOMIC_RELAXED, __HIP_MEMORY_SCOPE_AGENT);
            __hip_atomic_store(&F2[bid], MAGIC2 ^ (unsigned)bid, __ATOMIC_RELAXED, __HIP_MEMORY_SCOPE_AGENT);
        }
        return;
    }

    if (bid < 1280) {
        // ---- per-m mask softplus over L2/L3-resident proto ----
        const int m = bid - 1024;
        const int r = pos_idx[m * 3 + 0], h = pos_idx[m * 3 + 1], w = pos_idx[m * 3 + 2];
        const int off = (r << 2) * 4096 + h * 64 + w;
        const float c0 = map_coef[off];
        const float c1 = map_coef[off + 4096];
        const float c2 = map_coef[off + 8192];
        const float c3 = map_coef[off + 12288];
        float sp = 0.f;
#pragma unroll 4
        for (int i = 0; i < 16; ++i) {
            int f = (t + (i << 8)) << 2;
            float4 p0 = *reinterpret_cast<const float4*>(proto + f);
            float4 p1 = *reinterpret_cast<const float4*>(proto + 16384 + f);
            float4 p2 = *reinterpret_cast<const float4*>(proto + 32768 + f);
            float4 p3 = *reinterpret_cast<const float4*>(proto + 49152 + f);
            float L;
            L = fmaf(c3, p3.x, fmaf(c2, p2.x, fmaf(c1, p1.x, c0 * p0.x))); sp += softplusf(L);
            L = fmaf(c3, p3.y, fmaf(c2, p2.y, fmaf(c1, p1.y, c0 * p0.y))); sp += softplusf(L);
            L = fmaf(c3, p3.z, fmaf(c2, p2.z, fmaf(c1, p1.z, c0 * p0.z))); sp += softplusf(L);
            L = fmaf(c3, p3.w, fmaf(c2, p2.w, fmaf(c1, p1.w, c0 * p0.w))); sp += softplusf(L);
        }
        sp = wave_sum(sp);
        if (lane == 0) smem[wave][0] = sp;
        __syncthreads();
        if (t == 0) {
            SP[m] = smem[0][0] + smem[1][0] + smem[2][0] + smem[3][0];
            C4[(m << 2) + 0] = c0; C4[(m << 2) + 1] = c1;
            C4[(m << 2) + 2] = c2; C4[(m << 2) + 3] = c3;
            __threadfence();
            const int fi = 1024 + m;
            __hip_atomic_store(&F1[fi], MAGIC1 ^ (unsigned)fi, __ATOMIC_RELAXED, __HIP_MEMORY_SCOPE_AGENT);
            __hip_atomic_store(&F2[fi], MAGIC2 ^ (unsigned)fi, __ATOMIC_RELAXED, __HIP_MEMORY_SCOPE_AGENT);
        }
        return;
    }

    // ---- bid == 1280 (last dispatched): cls + loc, then poll, then combine ----
    __shared__ float s_cl;
    __shared__ float sT[128];
    {
        float sum;
        const int r = pos_idx[t * 3 + 0], h = pos_idx[t * 3 + 1], w = pos_idx[t * 3 + 2];
        const int hw = h * 64 + w;
        sum = softplusf(-map_class[r * 4096 + hw]);
        for (int j = 0; j < 3; ++j) {
            int n = t + (j << 8);
            int rn = neg_idx[n * 3 + 0], hn = neg_idx[n * 3 + 1], wn = neg_idx[n * 3 + 2];
            sum += softplusf(map_class[rn * 4096 + hn * 64 + wn]);
        }
        const float ach = anchor_center[hw];
        const float acw = anchor_center[4096 + hw];
        const float ah = anchor_box[r * 2 + 0];
        const float aw = anchor_box[r * 2 + 1];
        const int g = gt_idx[t];
        const float g0 = gt_boxes[g * 4 + 0], g1 = gt_boxes[g * 4 + 1];
        const float g2 = gt_boxes[g * 4 + 2], g3 = gt_boxes[g * 4 + 3];
        float tgt[4] = { (g0 - ach) / ah, (g1 - acw) / aw, log10f(g2 / ah), log10f(g3 / aw) };
#pragma unroll
        for (int j = 0; j < 4; ++j) {
            float d = map_box[(r * 4 + j) * 4096 + hw] - tgt[j];
            float a = fabsf(d);
            sum += (a < 1.0f) ? 0.5f * d * d : a - 0.5f;
        }
        sum = wave_sum(sum);
        if (lane == 0) smem[wave][0] = sum;
        __syncthreads();
        if (t == 0) s_cl = smem[0][0] + smem[1][0] + smem[2][0] + smem[3][0];
    }

    // ---- poll all 1280 producer flags (5 per thread) ----
    const int base = t * 5;
    int all_ready;
    do {
        int ready = 1;
#pragma unroll
        for (int j = 0; j < 5; ++j) {
            const int fi = base + j;
            unsigned a = __hip_atomic_load(&F1[fi], __ATOMIC_RELAXED, __HIP_MEMORY_SCOPE_AGENT);
            unsigned b = __hip_atomic_load(&F2[fi], __ATOMIC_RELAXED, __HIP_MEMORY_SCOPE_AGENT);
            if (a != (MAGIC1 ^ (unsigned)fi) || b != (MAGIC2 ^ (unsigned)fi)) ready = 0;
        }
        all_ready = __syncthreads_and(ready);
        if (!all_ready) __builtin_amdgcn_s_sleep(2);
    } while (!all_ready);
    __threadfence();

    // ---- dense combine (agent-scope loads bypass stale caches) ----
    if (t < 128) {                       // T[g][p] = sum of 32 chunk partials
        const int g = t >> 2, p = t & 3;
        float s = 0.f;
#pragma unroll
        for (int chunk = 0; chunk < 32; ++chunk)
            s += ws_load(&Tpart[(((g << 5) + chunk) << 2) + p]);
        sT[t] = s;
    }
    const int g = gt_idx[t];
    const float spm = ws_load(&SP[t]);
    const float c0 = ws_load(&C4[(t << 2) + 0]);
    const float c1 = ws_load(&C4[(t << 2) + 1]);
    const float c2 = ws_load(&C4[(t << 2) + 2]);
    const float c3 = ws_load(&C4[(t << 2) + 3]);
    __syncthreads();

    const float dotT = fmaf(c3, sT[(g << 2) + 3], fmaf(c2, sT[(g << 2) + 2],
                       fmaf(c1, sT[(g << 2) + 1], c0 * sT[(g << 2) + 0])));
    float contrib = (16.f * spm - dotT) * INV_TOTAL;
    contrib = wave_sum(contrib);
    if (lane == 0) smem[wave][0] = contrib;
    __syncthreads();
    if (t == 0)
        out[0] = s_cl + smem[0][0] + smem[1][0] + smem[2][0] + smem[3][0];
}

extern "C" void kernel_launch(void* const* d_in, const int* in_sizes, int n_in,
                              void* d_out, int out_size, void* d_ws, size_t ws_size,
                              hipStream_t stream) {
    const float* proto         = (const float*)d_in[0];
    const float* map_class     = (const float*)d_in[1];
    const float* map_box       = (const float*)d_in[2];
    const float* map_coef      = (const float*)d_in[3];
    const float* anchor_center = (const float*)d_in[4];
    const float* anchor_box    = (const float*)d_in[5];
    const float* gt_boxes      = (const float*)d_in[6];
    const float* gt_masks      = (const float*)d_in[7];
    const int*   pos_idx       = (const int*)d_in[8];
    const int*   gt_idx        = (const int*)d_in[9];
    const int*   neg_idx       = (const int*)d_in[10];

    float*    Tpart = (float*)d_ws;          // 4096 floats
    float*    SP    = Tpart + 4096;          // 256 floats
    float*    C4    = SP + 256;              // 1024 floats
    unsigned* F1    = (unsigned*)(C4 + 1024);// 1280 u32
    unsigned* F2    = F1 + 1280;             // 1280 u32
    float*    out   = (float*)d_out;

    k_all<<<1281, 256, 0, stream>>>(proto, map_coef, map_class, map_box,
                                    anchor_center, anchor_box, gt_boxes, gt_masks,
                                    pos_idx, gt_idx, neg_idx,
                                    Tpart, SP, C4, F1, F2, out);
}

// Round 3
// 101.138 us; speedup vs baseline: 1.3197x; 1.3197x over previous
//
#include <hip/hip_runtime.h>
#include <math.h>

// Problem: M=256 positives, 3M=768 negatives, NUM_GT=32,
// proto (4,128,128), maps (*,64,64), gt_masks (32,512,512).
//
// Mask-loss restructure (verified exact rounds 1-7):
//   mean(bce_m) = (1/512^2) * [ 16 * sum_{hw in 128^2} softplus(L_m[hw])
//                               - dot(coef_m, T[gt_m]) ]
//   T[g,p] = sum_{512^2} gt_masks[g] * proto[p, y/4, x/4]
//
// Structure: ONE dispatch, zero hot atomics, ZERO cache-maintenance insts.
// Lessons:
//  - R2-3: far-atomics funneled through one line across 8 XCDs serialize
//    (~25 us) — publish via disjoint plain stores.
//  - R6: nontemporal loads on the gt_masks stream regressed (+9 us): L3 was
//    absorbing ~half the 33.5 MB stream; keep default cache policy.
//  - R8: final made a pure dense combine; cls/loc runs in tmat's shadow.
//  - R9: tmat thread owns (col, 8 rows): rows sharing a proto cell summed
//    BEFORE multiply (8 proto loads / 8 FMA); 8 unrolled independent mask
//    loads; 1024 tmat blocks. Neutral-within-noise; kept.
//  - R10: FUSION VIA __threadfence REGRESSED 103->133. rocprof: k_all
//    55-62 us, FETCH halved to 17.6 MB, hbm ~300 GB/s -> L2-thrash
//    latency-bound. gfx950 agent seq_cst fence = buffer_wbl2 + buffer_inv;
//    1280 producer fences continuously invalidated every XCD's L2 (proto +
//    mask lines), turning the stream into L3-latency re-reads.
//  - R11 (this round): fence-free publish. Data -> relaxed AGENT atomic
//    stores (global_store sc0 sc1: write-through to coherence point, no L2
//    maintenance); ordering -> bare inline-asm s_waitcnt vmcnt(0) (LLVM's
//    agent release-store lowering minus wbl2, valid since all published
//    stores are write-through); flag -> relaxed AGENT store of MAGIC^i
//    (uniform poison can't match 1280 distinct values; no counter = no
//    zero-init; stale flags after skipped re-poison still correct since
//    producers rewrite identical values). Reducer polls/reads with relaxed
//    AGENT loads (sc0 sc1, served from coherence point, no buffer_inv).
//    No producer waits on the reducer -> deadlock-free at any occupancy.
//
//   k_all (1281 blocks): [0,1024): 16-row tmat slab partials -> Tpart;
//                        [1024,1280): per-m softplus -> SP, coef -> C4;
//                        1280: cls+loc, poll 1280 flags, combine -> out.

#define INV_TOTAL (1.0f / (262144.0f * 256.0f))
#define MAGIC 0xA5C3F00Du

__device__ __forceinline__ float softplusf(float x) {
    return fmaxf(x, 0.0f) + __logf(1.0f + __expf(-fabsf(x)));
}

__device__ __forceinline__ float wave_sum(float v) {
    v += __shfl_down(v, 32);
    v += __shfl_down(v, 16);
    v += __shfl_down(v, 8);
    v += __shfl_down(v, 4);
    v += __shfl_down(v, 2);
    v += __shfl_down(v, 1);
    return v;
}

__device__ __forceinline__ float sum4(float4 v) {
    return (v.x + v.y) + (v.z + v.w);
}

// Write-through (device-coherent) stores/loads: lower to sc0 sc1 accesses,
// no cache-maintenance instructions.
__device__ __forceinline__ void ws_storef(float* p, float v) {
    __hip_atomic_store(p, v, __ATOMIC_RELAXED, __HIP_MEMORY_SCOPE_AGENT);
}
__device__ __forceinline__ void ws_storeu(unsigned* p, unsigned v) {
    __hip_atomic_store(p, v, __ATOMIC_RELAXED, __HIP_MEMORY_SCOPE_AGENT);
}
__device__ __forceinline__ float ws_loadf(const float* p) {
    return __hip_atomic_load(p, __ATOMIC_RELAXED, __HIP_MEMORY_SCOPE_AGENT);
}
__device__ __forceinline__ unsigned ws_loadu(const unsigned* p) {
    return __hip_atomic_load(p, __ATOMIC_RELAXED, __HIP_MEMORY_SCOPE_AGENT);
}
__device__ __forceinline__ void drain_stores() {
    asm volatile("s_waitcnt vmcnt(0)" ::: "memory");
}

__global__ void __launch_bounds__(256)
k_all(const float* __restrict__ proto,
      const float* __restrict__ map_coef,
      const float* __restrict__ map_class,
      const float* __restrict__ map_box,
      const float* __restrict__ anchor_center,
      const float* __restrict__ anchor_box,
      const float* __restrict__ gt_boxes,
      const float* __restrict__ gt_masks,
      const int* __restrict__ pos_idx,
      const int* __restrict__ gt_idx,
      const int* __restrict__ neg_idx,
      float* __restrict__ Tpart,      // [1024*4] slab partials, slot = bid
      float* __restrict__ SP,         // [256] per-m softplus sums
      float* __restrict__ C4,         // [256*4] per-m coefs, dense
      unsigned* __restrict__ F,       // [1280] completion flags (MAGIC^i)
      float* __restrict__ out) {
    const int bid = blockIdx.x;
    const int t = threadIdx.x;
    const int wave = t >> 6, lane = t & 63;
    __shared__ float smem[4][4];

    if (bid < 1024) {
        // ---- tmat: partial T over a 16-row slab of gt_masks[g] ----
        // Thread owns float4-column k and 8 consecutive rows. Rows sharing a
        // proto cell (4 per cell) are summed BEFORE the proto multiply.
        const int g = bid >> 5, chunk = bid & 31;
        const float* mask = gt_masks + (size_t)g * (512 * 512);
        const int k  = t & 127;          // float4 column 0..127
        const int rg = t >> 7;           // row-group 0/1
        const int y0 = (chunk << 4) + (rg << 3);
        const float* mrow = mask + y0 * 512 + (k << 2);
        // 8 independent loads, all in flight
        float4 a0 = *reinterpret_cast<const float4*>(mrow);
        float4 a1 = *reinterpret_cast<const float4*>(mrow + 512);
        float4 a2 = *reinterpret_cast<const float4*>(mrow + 1024);
        float4 a3 = *reinterpret_cast<const float4*>(mrow + 1536);
        float4 a4 = *reinterpret_cast<const float4*>(mrow + 2048);
        float4 a5 = *reinterpret_cast<const float4*>(mrow + 2560);
        float4 a6 = *reinterpret_cast<const float4*>(mrow + 3072);
        float4 a7 = *reinterpret_cast<const float4*>(mrow + 3584);
        const float s0 = (sum4(a0) + sum4(a1)) + (sum4(a2) + sum4(a3));  // rows y0..y0+3
        const float s1 = (sum4(a4) + sum4(a5)) + (sum4(a6) + sum4(a7));  // rows y0+4..y0+7
        const int c0 = ((y0 >> 2) << 7) + k;   // proto cell for rows y0..y0+3
        const int c1 = c0 + 128;               // proto cell for rows y0+4..y0+7
        float tp0 = fmaf(s1, proto[c1],         s0 * proto[c0]);
        float tp1 = fmaf(s1, proto[16384 + c1], s0 * proto[16384 + c0]);
        float tp2 = fmaf(s1, proto[32768 + c1], s0 * proto[32768 + c0]);
        float tp3 = fmaf(s1, proto[49152 + c1], s0 * proto[49152 + c0]);
        tp0 = wave_sum(tp0); tp1 = wave_sum(tp1); tp2 = wave_sum(tp2); tp3 = wave_sum(tp3);
        if (lane == 0) { smem[wave][0] = tp0; smem[wave][1] = tp1; smem[wave][2] = tp2; smem[wave][3] = tp3; }
        __syncthreads();
        // Lanes 0..3 of wave 0 store as ONE wave instruction; lane 0's
        // vmcnt(0) therefore covers all four stores; then the flag goes out
        // write-through. No fences, no cache maintenance.
        if (t < 4)
            ws_storef(&Tpart[(bid << 2) + t],
                      smem[0][t] + smem[1][t] + smem[2][t] + smem[3][t]);
        if (t == 0) {
            drain_stores();
            ws_storeu(&F[bid], MAGIC ^ (unsigned)bid);
        }
        return;
    }

    if (bid < 1280) {
        // ---- per-m mask softplus over L2/L3-resident proto ----
        const int m = bid - 1024;
        const int r = pos_idx[m * 3 + 0], h = pos_idx[m * 3 + 1], w = pos_idx[m * 3 + 2];
        const int off = (r << 2) * 4096 + h * 64 + w;
        const float c0 = map_coef[off];
        const float c1 = map_coef[off + 4096];
        const float c2 = map_coef[off + 8192];
        const float c3 = map_coef[off + 12288];
        float sp = 0.f;
#pragma unroll 4
        for (int i = 0; i < 16; ++i) {
            int f = (t + (i << 8)) << 2;
            float4 p0 = *reinterpret_cast<const float4*>(proto + f);
            float4 p1 = *reinterpret_cast<const float4*>(proto + 16384 + f);
            float4 p2 = *reinterpret_cast<const float4*>(proto + 32768 + f);
            float4 p3 = *reinterpret_cast<const float4*>(proto + 49152 + f);
            float L;
            L = fmaf(c3, p3.x, fmaf(c2, p2.x, fmaf(c1, p1.x, c0 * p0.x))); sp += softplusf(L);
            L = fmaf(c3, p3.y, fmaf(c2, p2.y, fmaf(c1, p1.y, c0 * p0.y))); sp += softplusf(L);
            L = fmaf(c3, p3.z, fmaf(c2, p2.z, fmaf(c1, p1.z, c0 * p0.z))); sp += softplusf(L);
            L = fmaf(c3, p3.w, fmaf(c2, p2.w, fmaf(c1, p1.w, c0 * p0.w))); sp += softplusf(L);
        }
        sp = wave_sum(sp);
        if (lane == 0) smem[wave][0] = sp;
        __syncthreads();
        if (t == 0) {
            ws_storef(&SP[m], smem[0][0] + smem[1][0] + smem[2][0] + smem[3][0]);
            ws_storef(&C4[(m << 2) + 0], c0);
            ws_storef(&C4[(m << 2) + 1], c1);
            ws_storef(&C4[(m << 2) + 2], c2);
            ws_storef(&C4[(m << 2) + 3], c3);
            drain_stores();
            const int fi = 1024 + m;
            ws_storeu(&F[fi], MAGIC ^ (unsigned)fi);
        }
        return;
    }

    // ---- bid == 1280 (last dispatched): cls + loc, then poll, then combine ----
    __shared__ float s_cl;
    __shared__ float sT[128];
    {
        float sum;
        const int r = pos_idx[t * 3 + 0], h = pos_idx[t * 3 + 1], w = pos_idx[t * 3 + 2];
        const int hw = h * 64 + w;
        sum = softplusf(-map_class[r * 4096 + hw]);
        for (int j = 0; j < 3; ++j) {
            int n = t + (j << 8);
            int rn = neg_idx[n * 3 + 0], hn = neg_idx[n * 3 + 1], wn = neg_idx[n * 3 + 2];
            sum += softplusf(map_class[rn * 4096 + hn * 64 + wn]);
        }
        const float ach = anchor_center[hw];
        const float acw = anchor_center[4096 + hw];
        const float ah = anchor_box[r * 2 + 0];
        const float aw = anchor_box[r * 2 + 1];
        const int g = gt_idx[t];
        const float g0 = gt_boxes[g * 4 + 0], g1 = gt_boxes[g * 4 + 1];
        const float g2 = gt_boxes[g * 4 + 2], g3 = gt_boxes[g * 4 + 3];
        float tgt[4] = { (g0 - ach) / ah, (g1 - acw) / aw, log10f(g2 / ah), log10f(g3 / aw) };
#pragma unroll
        for (int j = 0; j < 4; ++j) {
            float d = map_box[(r * 4 + j) * 4096 + hw] - tgt[j];
            float a = fabsf(d);
            sum += (a < 1.0f) ? 0.5f * d * d : a - 0.5f;
        }
        sum = wave_sum(sum);
        if (lane == 0) smem[wave][0] = sum;
        __syncthreads();
        if (t == 0) s_cl = smem[0][0] + smem[1][0] + smem[2][0] + smem[3][0];
    }

    // ---- poll all 1280 producer flags (5 per thread, coherence-point loads) ----
    const int base = t * 5;
    int all_ready;
    do {
        int ready = 1;
#pragma unroll
        for (int j = 0; j < 5; ++j) {
            const int fi = base + j;
            if (ws_loadu(&F[fi]) != (MAGIC ^ (unsigned)fi)) ready = 0;
        }
        all_ready = __syncthreads_and(ready);
        if (!all_ready) __builtin_amdgcn_s_sleep(2);
    } while (!all_ready);

    // ---- dense combine (coherence-point loads; no buffer_inv needed) ----
    if (t < 128) {                       // T[g][p] = sum of 32 chunk partials
        const int g = t >> 2, p = t & 3;
        float s = 0.f;
#pragma unroll
        for (int chunk = 0; chunk < 32; ++chunk)
            s += ws_loadf(&Tpart[(((g << 5) + chunk) << 2) + p]);
        sT[t] = s;
    }
    const int g = gt_idx[t];
    const float spm = ws_loadf(&SP[t]);
    const float c0 = ws_loadf(&C4[(t << 2) + 0]);
    const float c1 = ws_loadf(&C4[(t << 2) + 1]);
    const float c2 = ws_loadf(&C4[(t << 2) + 2]);
    const float c3 = ws_loadf(&C4[(t << 2) + 3]);
    __syncthreads();

    const float dotT = fmaf(c3, sT[(g << 2) + 3], fmaf(c2, sT[(g << 2) + 2],
                       fmaf(c1, sT[(g << 2) + 1], c0 * sT[(g << 2) + 0])));
    float contrib = (16.f * spm - dotT) * INV_TOTAL;
    contrib = wave_sum(contrib);
    if (lane == 0) smem[wave][0] = contrib;
    __syncthreads();
    if (t == 0)
        out[0] = s_cl + smem[0][0] + smem[1][0] + smem[2][0] + smem[3][0];
}

extern "C" void kernel_launch(void* const* d_in, const int* in_sizes, int n_in,
                              void* d_out, int out_size, void* d_ws, size_t ws_size,
                              hipStream_t stream) {
    const float* proto         = (const float*)d_in[0];
    const float* map_class     = (const float*)d_in[1];
    const float* map_box       = (const float*)d_in[2];
    const float* map_coef      = (const float*)d_in[3];
    const float* anchor_center = (const float*)d_in[4];
    const float* anchor_box    = (const float*)d_in[5];
    const float* gt_boxes      = (const float*)d_in[6];
    const float* gt_masks      = (const float*)d_in[7];
    const int*   pos_idx       = (const int*)d_in[8];
    const int*   gt_idx        = (const int*)d_in[9];
    const int*   neg_idx       = (const int*)d_in[10];

    float*    Tpart = (float*)d_ws;          // 4096 floats
    float*    SP    = Tpart + 4096;          // 256 floats
    float*    C4    = SP + 256;              // 1024 floats
    unsigned* F     = (unsigned*)(C4 + 1024);// 1280 u32
    float*    out   = (float*)d_out;

    k_all<<<1281, 256, 0, stream>>>(proto, map_coef, map_class, map_box,
                                    anchor_center, anchor_box, gt_boxes, gt_masks,
                                    pos_idx, gt_idx, neg_idx,
                                    Tpart, SP, C4, F, out);
}